// Round 2
// baseline (60632.159 us; speedup 1.0000x reference)
//
#include <hip/hip_runtime.h>
#include <math.h>

// ---------------- problem constants ----------------
constexpr int LD       = 768;     // H
constexpr int BKK      = 16;      // GEMM k-tile
constexpr int KSTEPS   = LD / BKK;
constexpr int PAD_ROW  = 200000;  // emb_table row for masked neighbors (== NODE_NUM)
constexpr int NTOT     = 16384;   // B*K seed nodes
constexpr int FNB      = 5;       // fanout
constexpr int DHEAD    = 96;
constexpr int MASK_N   = 2 * NTOT * FNB;   // 163840 mask elements

// =====================================================================
// Mask layout detection (graph-safe, device-only).
// If the bool mask was uploaded as raw bytes, reading it as u32 words
// shows values > 1 in ~49% of words. If widened to int32, all words are
// 0/1. Scan 32768 words (128KB, within the buffer under BOTH layouts).
// flag=1 -> byte layout, flag=0 -> int32 layout.
// =====================================================================
__global__ __launch_bounds__(256)
void detect_mask(const unsigned int* __restrict__ m, int* __restrict__ flag)
{
    __shared__ int found;
    if (threadIdx.x == 0) found = 0;
    __syncthreads();
    int f = 0;
    for (int i = threadIdx.x; i < 32768; i += 256) f |= (m[i] > 1u);
    if (f) atomicOr(&found, 1);
    __syncthreads();
    if (threadIdx.x == 0) *flag = found;
}

__global__ __launch_bounds__(256)
void canon_mask(const void* __restrict__ mraw, const int* __restrict__ flag,
                unsigned char* __restrict__ outm)
{
    const int i = blockIdx.x * 256 + threadIdx.x;   // grid sized exactly
    const unsigned char v = (*flag)
        ? ((const unsigned char*)mraw)[i]
        : (unsigned char)(((const int*)mraw)[i] != 0);
    outm[i] = v;
}

// =====================================================================
// 128x128 tiled fp32 GEMM, 256 threads, 8x8 micro-tile per thread.
// A is [M,768] row-major (or emb_table with gathered rows when GATHER).
// TRANSB=false -> C=A@B ; TRANSB=true -> C=A@B^T.  N=K=768.
// =====================================================================
template<bool TRANSB, bool GATHER>
__global__ __launch_bounds__(256, 2)
void gemm_f32(const float* __restrict__ A,
              const int* __restrict__ gidx,
              const unsigned char* __restrict__ gmask,
              int growoff,
              const float* __restrict__ Bm,
              float* __restrict__ C)
{
    __shared__ float As[BKK][132];
    __shared__ float Bs[BKK][132];

    const int tid   = threadIdx.x;
    const int tx    = tid & 15;
    const int ty    = tid >> 4;
    const int mBase = blockIdx.x * 128;
    const int nBase = blockIdx.y * 128;

    const int arow = tid >> 2;          // 0..63
    const int acol = (tid & 3) << 2;    // k-offset, float4

    const float* aptr0;
    const float* aptr1;
    if constexpr (GATHER) {
        const int g0 = growoff + mBase + arow;
        const int g1 = g0 + 64;
        const int i0 = gmask[g0] ? PAD_ROW : gidx[g0];
        const int i1 = gmask[g1] ? PAD_ROW : gidx[g1];
        aptr0 = A + (size_t)i0 * LD + acol;
        aptr1 = A + (size_t)i1 * LD + acol;
    } else {
        aptr0 = A + (size_t)(mBase + arow) * LD + acol;
        aptr1 = aptr0 + (size_t)64 * LD;
    }

    const float* bptr0;
    const float* bptr1;
    if constexpr (!TRANSB) {
        bptr0 = Bm + (size_t)(tid >> 5) * LD + nBase + ((tid & 31) << 2);
        bptr1 = bptr0 + (size_t)8 * LD;
    } else {
        bptr0 = Bm + (size_t)(nBase + (tid >> 2)) * LD + ((tid & 3) << 2);
        bptr1 = bptr0 + (size_t)64 * LD;
    }

    float4 pa0, pa1, pb0, pb1;

    auto loadG = [&](int ks) {
        const int ko = ks * BKK;
        pa0 = *(const float4*)(aptr0 + ko);
        pa1 = *(const float4*)(aptr1 + ko);
        if constexpr (!TRANSB) {
            pb0 = *(const float4*)(bptr0 + (size_t)ko * LD);
            pb1 = *(const float4*)(bptr1 + (size_t)ko * LD);
        } else {
            pb0 = *(const float4*)(bptr0 + ko);
            pb1 = *(const float4*)(bptr1 + ko);
        }
    };
    auto storeS = [&]() {
        As[acol + 0][arow] = pa0.x; As[acol + 1][arow] = pa0.y;
        As[acol + 2][arow] = pa0.z; As[acol + 3][arow] = pa0.w;
        As[acol + 0][arow + 64] = pa1.x; As[acol + 1][arow + 64] = pa1.y;
        As[acol + 2][arow + 64] = pa1.z; As[acol + 3][arow + 64] = pa1.w;
        if constexpr (!TRANSB) {
            const int k0 = tid >> 5, n0 = (tid & 31) << 2;
            *(float4*)&Bs[k0][n0]     = pb0;
            *(float4*)&Bs[k0 + 8][n0] = pb1;
        } else {
            const int nr = tid >> 2, k0 = (tid & 3) << 2;
            Bs[k0 + 0][nr] = pb0.x; Bs[k0 + 1][nr] = pb0.y;
            Bs[k0 + 2][nr] = pb0.z; Bs[k0 + 3][nr] = pb0.w;
            Bs[k0 + 0][nr + 64] = pb1.x; Bs[k0 + 1][nr + 64] = pb1.y;
            Bs[k0 + 2][nr + 64] = pb1.z; Bs[k0 + 3][nr + 64] = pb1.w;
        }
    };

    float acc[8][8] = {};

    loadG(0); storeS(); __syncthreads();
    for (int ks = 0; ks < KSTEPS; ++ks) {
        const bool more = (ks + 1 < KSTEPS);
        if (more) loadG(ks + 1);
        #pragma unroll
        for (int kk = 0; kk < BKK; ++kk) {
            const float4 a0 = *(const float4*)&As[kk][ty << 3];
            const float4 a1 = *(const float4*)&As[kk][(ty << 3) + 4];
            const float4 b0 = *(const float4*)&Bs[kk][tx << 3];
            const float4 b1 = *(const float4*)&Bs[kk][(tx << 3) + 4];
            const float av[8] = {a0.x, a0.y, a0.z, a0.w, a1.x, a1.y, a1.z, a1.w};
            const float bv[8] = {b0.x, b0.y, b0.z, b0.w, b1.x, b1.y, b1.z, b1.w};
            #pragma unroll
            for (int i = 0; i < 8; ++i)
                #pragma unroll
                for (int j = 0; j < 8; ++j)
                    acc[i][j] = fmaf(av[i], bv[j], acc[i][j]);
        }
        __syncthreads();
        if (more) { storeS(); __syncthreads(); }
    }

    float* cp = C + (size_t)(mBase + (ty << 3)) * LD + nBase + (tx << 3);
    #pragma unroll
    for (int i = 0; i < 8; ++i) {
        float4 v0; v0.x = acc[i][0]; v0.y = acc[i][1]; v0.z = acc[i][2]; v0.w = acc[i][3];
        float4 v1; v1.x = acc[i][4]; v1.y = acc[i][5]; v1.z = acc[i][6]; v1.w = acc[i][7];
        *(float4*)(cp + (size_t)i * LD)     = v0;
        *(float4*)(cp + (size_t)i * LD + 4) = v1;
    }
}

// =====================================================================
// h = emb_table[ids] row gather (float4 granularity), chunk-local
// =====================================================================
__global__ __launch_bounds__(256)
void gather_rows(const float* __restrict__ table, const int* __restrict__ ids,
                 float* __restrict__ outb)
{
    const int i = blockIdx.x * 256 + threadIdx.x;      // float4 index, exact grid
    const int row = i / 192;                           // 192 float4 per row
    const int c   = i - row * 192;
    ((float4*)outb)[(size_t)row * 192 + c] =
        ((const float4*)table)[(size_t)ids[row] * 192 + c];
}

// =====================================================================
// Per-node attention: one 64-lane wave per (chunk-local) node.
// lane = head*8 + seg ; covers cols [head*96 + seg*12, +12)
// =====================================================================
__global__ __launch_bounds__(256)
void attn_kernel(const float* __restrict__ Q, const float* __restrict__ Kc,
                 const float* __restrict__ Vc, float* __restrict__ agg,
                 int accumulate)
{
    const int n    = blockIdx.x * 4 + (threadIdx.x >> 6);  // chunk-local node
    const int lane = threadIdx.x & 63;
    const int col  = (lane >> 3) * DHEAD + (lane & 7) * 12;

    const float* qp = Q + (size_t)n * LD + col;
    float q[12];
    *(float4*)&q[0] = *(const float4*)(qp);
    *(float4*)&q[4] = *(const float4*)(qp + 4);
    *(float4*)&q[8] = *(const float4*)(qp + 8);

    float sc[FNB];
    float vr[FNB][12];
    #pragma unroll
    for (int f = 0; f < FNB; ++f) {
        const size_t roff = ((size_t)n * FNB + f) * LD + col;
        const float* kp = Kc + roff;
        const float* vp = Vc + roff;
        float kx[12];
        *(float4*)&kx[0] = *(const float4*)(kp);
        *(float4*)&kx[4] = *(const float4*)(kp + 4);
        *(float4*)&kx[8] = *(const float4*)(kp + 8);
        *(float4*)&vr[f][0] = *(const float4*)(vp);
        *(float4*)&vr[f][4] = *(const float4*)(vp + 4);
        *(float4*)&vr[f][8] = *(const float4*)(vp + 8);
        float p = 0.f;
        #pragma unroll
        for (int t = 0; t < 12; ++t) p = fmaf(q[t], kx[t], p);
        p += __shfl_xor(p, 1, 64);
        p += __shfl_xor(p, 2, 64);
        p += __shfl_xor(p, 4, 64);                 // head-sum in all 8 lanes
        sc[f] = p * 0.10206207262f;                // 1/sqrt(96)
    }

    float mx = sc[0];
    #pragma unroll
    for (int f = 1; f < FNB; ++f) mx = fmaxf(mx, sc[f]);
    float e[FNB], ssum = 0.f;
    #pragma unroll
    for (int f = 0; f < FNB; ++f) { e[f] = __expf(sc[f] - mx); ssum += e[f]; }
    const float inv = 1.f / ssum;

    float o[12] = {};
    #pragma unroll
    for (int f = 0; f < FNB; ++f) {
        const float a = e[f] * inv;
        #pragma unroll
        for (int t = 0; t < 12; ++t) o[t] = fmaf(a, vr[f][t], o[t]);
    }

    float* ap = agg + (size_t)n * LD + col;
    if (accumulate) {
        #pragma unroll
        for (int t = 0; t < 12; ++t) ap[t] += o[t];
    } else {
        *(float4*)(ap)     = *(float4*)&o[0];
        *(float4*)(ap + 4) = *(float4*)&o[4];
        *(float4*)(ap + 8) = *(float4*)&o[8];
    }
}

// =====================================================================
// h = LayerNorm(h + U) * g + b     (one wave per row)
// =====================================================================
__global__ __launch_bounds__(64)
void ln_residual(float* __restrict__ hbuf, const float* __restrict__ U,
                 const float* __restrict__ g, const float* __restrict__ b)
{
    const int n = blockIdx.x, lane = threadIdx.x;
    float x[12];
    #pragma unroll
    for (int c = 0; c < 3; ++c) {
        const int col = lane * 4 + c * 256;
        const float4 hv = *(const float4*)(hbuf + (size_t)n * LD + col);
        const float4 uv = *(const float4*)(U    + (size_t)n * LD + col);
        x[c*4+0] = hv.x + uv.x; x[c*4+1] = hv.y + uv.y;
        x[c*4+2] = hv.z + uv.z; x[c*4+3] = hv.w + uv.w;
    }
    float s = 0.f;
    #pragma unroll
    for (int t = 0; t < 12; ++t) s += x[t];
    for (int m = 1; m < 64; m <<= 1) s += __shfl_xor(s, m, 64);
    const float mean = s * (1.0f / LD);
    float v = 0.f;
    #pragma unroll
    for (int t = 0; t < 12; ++t) { const float d = x[t] - mean; v = fmaf(d, d, v); }
    for (int m = 1; m < 64; m <<= 1) v += __shfl_xor(v, m, 64);
    const float rinv = rsqrtf(v * (1.0f / LD) + 1e-5f);
    #pragma unroll
    for (int c = 0; c < 3; ++c) {
        const int col = lane * 4 + c * 256;
        const float4 gv = *(const float4*)(g + col);
        const float4 bv = *(const float4*)(b + col);
        float4 y;
        y.x = (x[c*4+0] - mean) * rinv * gv.x + bv.x;
        y.y = (x[c*4+1] - mean) * rinv * gv.y + bv.y;
        y.z = (x[c*4+2] - mean) * rinv * gv.z + bv.z;
        y.w = (x[c*4+3] - mean) * rinv * gv.w + bv.w;
        *(float4*)(hbuf + (size_t)n * LD + col) = y;
    }
}

// =====================================================================
// out[n] = dot(h[n,:], word[n>>3,:])   (one wave per output, chunk-local)
// =====================================================================
__global__ __launch_bounds__(256)
void final_dot(const float* __restrict__ hbuf, const float* __restrict__ word,
               float* __restrict__ outb)
{
    const int n    = blockIdx.x * 4 + (threadIdx.x >> 6);
    const int lane = threadIdx.x & 63;
    const int bidx = n >> 3;
    float s = 0.f;
    #pragma unroll
    for (int c = 0; c < 3; ++c) {
        const int col = lane * 4 + c * 256;
        const float4 hv = *(const float4*)(hbuf + (size_t)n    * LD + col);
        const float4 wv = *(const float4*)(word + (size_t)bidx * LD + col);
        s = fmaf(hv.x, wv.x, s); s = fmaf(hv.y, wv.y, s);
        s = fmaf(hv.z, wv.z, s); s = fmaf(hv.w, wv.w, s);
    }
    for (int m = 1; m < 64; m <<= 1) s += __shfl_xor(s, m, 64);
    if (lane == 0) outb[n] = s;
}

// =====================================================================
extern "C" void kernel_launch(void* const* d_in, const int* in_sizes, int n_in,
                              void* d_out, int out_size, void* d_ws, size_t ws_size,
                              hipStream_t stream)
{
    (void)in_sizes; (void)n_in; (void)out_size;
    const float* emb      = (const float*)d_in[0];
    const float* aver     = (const float*)d_in[1];
    const float* Wt       = (const float*)d_in[2];
    const float* Wq       = (const float*)d_in[3];
    const float* Wk       = (const float*)d_in[4];
    const float* Wv       = (const float*)d_in[5];
    const float* Wo       = (const float*)d_in[6];
    const float* ln_g     = (const float*)d_in[7];
    const float* ln_b     = (const float*)d_in[8];
    const int*   id_pairs = (const int*)d_in[9];
    const int*   src_ids  = (const int*)d_in[10];
    const void*  mask_raw = d_in[11];                 // layout detected at runtime
    float* outp = (float*)d_out;

    // ---- workspace carve: header (flag + canonical mask) + chunk buffers ----
    char* wp = (char*)d_ws;
    int* mflag = (int*)wp;                 wp += 4096;
    unsigned char* mcanon = (unsigned char*)wp; wp += 164096;   // 163840 rounded up
    const size_t head_bytes = 4096 + 164096;

    // per-node bytes: h,Q,agg (3) + K,V (10) + word (1/8)  -> 13.125 * 3072
    int NC = NTOT;                                              // nodes per chunk
    while (NC > 1024 && head_bytes + (size_t)NC * 40320 + 4096 > ws_size) NC >>= 1;

    float* wordb = (float*)wp; wp += (size_t)(NC / 8) * LD * 4;
    float* hb    = (float*)wp; wp += (size_t)NC * LD * 4;
    float* Qb    = (float*)wp; wp += (size_t)NC * LD * 4;       // also holds U
    float* aggb  = (float*)wp; wp += (size_t)NC * LD * 4;
    float* Kc    = (float*)wp; wp += (size_t)NC * FNB * LD * 4;
    float* Vc    = (float*)wp;

    // ---- mask canonicalization (byte vs int32 layout) ----
    detect_mask<<<1, 256, 0, stream>>>((const unsigned int*)mask_raw, mflag);
    canon_mask<<<MASK_N / 256, 256, 0, stream>>>(mask_raw, mflag, mcanon);

    for (int c0 = 0; c0 < NTOT; c0 += NC) {
        // word chunk = aver[b0:b0+NC/8] @ Wt^T
        gemm_f32<true, false><<<dim3((NC / 8) / 128, 6), 256, 0, stream>>>(
            aver + (size_t)(c0 / 8) * LD, nullptr, nullptr, 0, Wt, wordb);

        // h chunk = emb_table[dst chunk]
        gather_rows<<<(NC * (LD / 4)) / 256, 256, 0, stream>>>(
            emb, id_pairs + c0, hb);

        for (int l = 0; l < 2; ++l) {
            for (int r = 0; r < 2; ++r) {
                const float* wq = Wq + (size_t)(l * 2 + r) * LD * LD;
                const float* wk = Wk + (size_t)(l * 2 + r) * LD * LD;
                const float* wv = Wv + (size_t)(l * 2 + r) * LD * LD;
                const int groff = r * NTOT * FNB + c0 * FNB;

                gemm_f32<false, false><<<dim3(NC / 128, 6), 256, 0, stream>>>(
                    hb, nullptr, nullptr, 0, wq, Qb);
                gemm_f32<false, true><<<dim3((NC * FNB) / 128, 6), 256, 0, stream>>>(
                    emb, src_ids, mcanon, groff, wk, Kc);
                gemm_f32<false, true><<<dim3((NC * FNB) / 128, 6), 256, 0, stream>>>(
                    emb, src_ids, mcanon, groff, wv, Vc);
                attn_kernel<<<NC / 4, 256, 0, stream>>>(Qb, Kc, Vc, aggb, r);
            }
            gemm_f32<false, false><<<dim3(NC / 128, 6), 256, 0, stream>>>(
                aggb, nullptr, nullptr, 0, Wo + (size_t)l * LD * LD, Qb);
            ln_residual<<<NC, 64, 0, stream>>>(hb, Qb, ln_g + (size_t)l * LD,
                                               ln_b + (size_t)l * LD);
        }

        final_dot<<<NC / 4, 256, 0, stream>>>(hb, wordb, outp + c0);
    }
}

// Round 4
// 20521.680 us; speedup vs baseline: 2.9545x; 2.9545x over previous
//
#include <hip/hip_runtime.h>
#include <math.h>

// ---------------- problem constants ----------------
constexpr int LD       = 768;     // H
constexpr int QKS      = 6144;    // qk/y row stride = 8*768
constexpr int BKK      = 16;      // GEMM k-tile
constexpr int KSTEPS   = LD / BKK;
constexpr int PAD_ROW  = 200000;  // emb_table row for masked neighbors
constexpr int NTOT     = 16384;   // B*K seed nodes
constexpr int FNB      = 5;       // fanout
constexpr int MASK_N   = 2 * NTOT * FNB;

// =====================================================================
// Mask layout detection (byte vs int32 bool) — graph-safe, device-only.
// =====================================================================
__global__ __launch_bounds__(256)
void detect_mask(const unsigned int* __restrict__ m, int* __restrict__ flag)
{
    __shared__ int found;
    if (threadIdx.x == 0) found = 0;
    __syncthreads();
    int f = 0;
    for (int i = threadIdx.x; i < 32768; i += 256) f |= (m[i] > 1u);
    if (f) atomicOr(&found, 1);
    __syncthreads();
    if (threadIdx.x == 0) *flag = found;
}

__global__ __launch_bounds__(256)
void canon_mask(const void* __restrict__ mraw, const int* __restrict__ flag,
                unsigned char* __restrict__ outm)
{
    const int i = blockIdx.x * 256 + threadIdx.x;
    const unsigned char v = (*flag)
        ? ((const unsigned char*)mraw)[i]
        : (unsigned char)(((const int*)mraw)[i] != 0);
    outm[i] = v;
}

// =====================================================================
// 128x128 tiled fp32 GEMM, 256 threads, 8x8 micro-tile.
// A [M,768] row-major. TRANSB=false -> C=A@B ; true -> C=A@B^T. N=K=768.
// =====================================================================
template<bool TRANSB>
__global__ __launch_bounds__(256, 2)
void gemm_f32(const float* __restrict__ A, const float* __restrict__ Bm,
              float* __restrict__ C)
{
    __shared__ float As[BKK][132];
    __shared__ float Bs[BKK][132];

    const int tid   = threadIdx.x;
    const int tx    = tid & 15;
    const int ty    = tid >> 4;
    const int mBase = blockIdx.x * 128;
    const int nBase = blockIdx.y * 128;

    const int arow = tid >> 2;
    const int acol = (tid & 3) << 2;

    const float* aptr0 = A + (size_t)(mBase + arow) * LD + acol;
    const float* aptr1 = aptr0 + (size_t)64 * LD;

    const float* bptr0;
    const float* bptr1;
    if constexpr (!TRANSB) {
        bptr0 = Bm + (size_t)(tid >> 5) * LD + nBase + ((tid & 31) << 2);
        bptr1 = bptr0 + (size_t)8 * LD;
    } else {
        bptr0 = Bm + (size_t)(nBase + (tid >> 2)) * LD + ((tid & 3) << 2);
        bptr1 = bptr0 + (size_t)64 * LD;
    }

    float4 pa0, pa1, pb0, pb1;

    auto loadG = [&](int ks) {
        const int ko = ks * BKK;
        pa0 = *(const float4*)(aptr0 + ko);
        pa1 = *(const float4*)(aptr1 + ko);
        if constexpr (!TRANSB) {
            pb0 = *(const float4*)(bptr0 + (size_t)ko * LD);
            pb1 = *(const float4*)(bptr1 + (size_t)ko * LD);
        } else {
            pb0 = *(const float4*)(bptr0 + ko);
            pb1 = *(const float4*)(bptr1 + ko);
        }
    };
    auto storeS = [&]() {
        As[acol + 0][arow] = pa0.x; As[acol + 1][arow] = pa0.y;
        As[acol + 2][arow] = pa0.z; As[acol + 3][arow] = pa0.w;
        As[acol + 0][arow + 64] = pa1.x; As[acol + 1][arow + 64] = pa1.y;
        As[acol + 2][arow + 64] = pa1.z; As[acol + 3][arow + 64] = pa1.w;
        if constexpr (!TRANSB) {
            const int k0 = tid >> 5, n0 = (tid & 31) << 2;
            *(float4*)&Bs[k0][n0]     = pb0;
            *(float4*)&Bs[k0 + 8][n0] = pb1;
        } else {
            const int nr = tid >> 2, k0 = (tid & 3) << 2;
            Bs[k0 + 0][nr] = pb0.x; Bs[k0 + 1][nr] = pb0.y;
            Bs[k0 + 2][nr] = pb0.z; Bs[k0 + 3][nr] = pb0.w;
            Bs[k0 + 0][nr + 64] = pb1.x; Bs[k0 + 1][nr + 64] = pb1.y;
            Bs[k0 + 2][nr + 64] = pb1.z; Bs[k0 + 3][nr + 64] = pb1.w;
        }
    };

    float acc[8][8] = {};

    loadG(0); storeS(); __syncthreads();
    for (int ks = 0; ks < KSTEPS; ++ks) {
        const bool more = (ks + 1 < KSTEPS);
        if (more) loadG(ks + 1);
        #pragma unroll
        for (int kk = 0; kk < BKK; ++kk) {
            const float4 a0 = *(const float4*)&As[kk][ty << 3];
            const float4 a1 = *(const float4*)&As[kk][(ty << 3) + 4];
            const float4 b0 = *(const float4*)&Bs[kk][tx << 3];
            const float4 b1 = *(const float4*)&Bs[kk][(tx << 3) + 4];
            const float av[8] = {a0.x, a0.y, a0.z, a0.w, a1.x, a1.y, a1.z, a1.w};
            const float bv[8] = {b0.x, b0.y, b0.z, b0.w, b1.x, b1.y, b1.z, b1.w};
            #pragma unroll
            for (int i = 0; i < 8; ++i)
                #pragma unroll
                for (int j = 0; j < 8; ++j)
                    acc[i][j] = fmaf(av[i], bv[j], acc[i][j]);
        }
        __syncthreads();
        if (more) { storeS(); __syncthreads(); }
    }

    float* cp = C + (size_t)(mBase + (ty << 3)) * LD + nBase + (tx << 3);
    #pragma unroll
    for (int i = 0; i < 8; ++i) {
        float4 v0; v0.x = acc[i][0]; v0.y = acc[i][1]; v0.z = acc[i][2]; v0.w = acc[i][3];
        float4 v1; v1.x = acc[i][4]; v1.y = acc[i][5]; v1.z = acc[i][6]; v1.w = acc[i][7];
        *(float4*)(cp + (size_t)i * LD)     = v0;
        *(float4*)(cp + (size_t)i * LD + 4) = v1;
    }
}

// =====================================================================
// qk[n,h,c] = sum_d Q[n,h*96+d] * Wk[c,h*96+d]   (K=96, per-head TRANSB)
// tile 128(n) x 128(c), head = blockIdx.z, C row stride QKS.
// =====================================================================
__global__ __launch_bounds__(256, 2)
void gemm_qk(const float* __restrict__ Q, const float* __restrict__ Wk,
             float* __restrict__ qk)
{
    __shared__ float As[BKK][132];
    __shared__ float Bs[BKK][132];

    const int tid   = threadIdx.x;
    const int tx    = tid & 15;
    const int ty    = tid >> 4;
    const int mBase = blockIdx.x * 128;
    const int cBase = blockIdx.y * 128;
    const int koff  = blockIdx.z * 96;

    const int arow = tid >> 2;
    const int acol = (tid & 3) << 2;

    const float* ap0 = Q  + (size_t)(mBase + arow) * LD + koff + acol;
    const float* ap1 = ap0 + (size_t)64 * LD;
    const float* bp0 = Wk + (size_t)(cBase + arow) * LD + koff + acol;
    const float* bp1 = bp0 + (size_t)64 * LD;

    float4 pa0, pa1, pb0, pb1;
    auto loadG = [&](int ks) {
        const int ko = ks * BKK;
        pa0 = *(const float4*)(ap0 + ko);
        pa1 = *(const float4*)(ap1 + ko);
        pb0 = *(const float4*)(bp0 + ko);
        pb1 = *(const float4*)(bp1 + ko);
    };
    auto storeS = [&]() {
        As[acol + 0][arow] = pa0.x; As[acol + 1][arow] = pa0.y;
        As[acol + 2][arow] = pa0.z; As[acol + 3][arow] = pa0.w;
        As[acol + 0][arow + 64] = pa1.x; As[acol + 1][arow + 64] = pa1.y;
        As[acol + 2][arow + 64] = pa1.z; As[acol + 3][arow + 64] = pa1.w;
        Bs[acol + 0][arow] = pb0.x; Bs[acol + 1][arow] = pb0.y;
        Bs[acol + 2][arow] = pb0.z; Bs[acol + 3][arow] = pb0.w;
        Bs[acol + 0][arow + 64] = pb1.x; Bs[acol + 1][arow + 64] = pb1.y;
        Bs[acol + 2][arow + 64] = pb1.z; Bs[acol + 3][arow + 64] = pb1.w;
    };

    float acc[8][8] = {};

    loadG(0); storeS(); __syncthreads();
    for (int ks = 0; ks < 6; ++ks) {           // K = 96
        const bool more = (ks + 1 < 6);
        if (more) loadG(ks + 1);
        #pragma unroll
        for (int kk = 0; kk < BKK; ++kk) {
            const float4 a0 = *(const float4*)&As[kk][ty << 3];
            const float4 a1 = *(const float4*)&As[kk][(ty << 3) + 4];
            const float4 b0 = *(const float4*)&Bs[kk][tx << 3];
            const float4 b1 = *(const float4*)&Bs[kk][(tx << 3) + 4];
            const float av[8] = {a0.x, a0.y, a0.z, a0.w, a1.x, a1.y, a1.z, a1.w};
            const float bv[8] = {b0.x, b0.y, b0.z, b0.w, b1.x, b1.y, b1.z, b1.w};
            #pragma unroll
            for (int i = 0; i < 8; ++i)
                #pragma unroll
                for (int j = 0; j < 8; ++j)
                    acc[i][j] = fmaf(av[i], bv[j], acc[i][j]);
        }
        __syncthreads();
        if (more) { storeS(); __syncthreads(); }
    }

    float* cp = qk + (size_t)(mBase + (ty << 3)) * QKS
                   + (size_t)blockIdx.z * LD + cBase + (tx << 3);
    #pragma unroll
    for (int i = 0; i < 8; ++i) {
        float4 v0; v0.x = acc[i][0]; v0.y = acc[i][1]; v0.z = acc[i][2]; v0.w = acc[i][3];
        float4 v1; v1.x = acc[i][4]; v1.y = acc[i][5]; v1.z = acc[i][6]; v1.w = acc[i][7];
        *(float4*)(cp + (size_t)i * QKS)     = v0;
        *(float4*)(cp + (size_t)i * QKS + 4) = v1;
    }
}

// =====================================================================
// Fused scores/softmax/y: one wave per node, lane owns 12 c-columns.
// reads qk[n,h,:], gathers sf[n,f,:] from emb; writes y over qk in place.
// =====================================================================
__global__ __launch_bounds__(256)
void scores_y(const float* __restrict__ emb, const int* __restrict__ src,
              const unsigned char* __restrict__ msk, int groff,
              float* __restrict__ qky)
{
    const int n    = blockIdx.x * 4 + (threadIdx.x >> 6);
    const int lane = threadIdx.x & 63;
    const int c0   = lane * 12;

    float sf[FNB][12];
    #pragma unroll
    for (int f = 0; f < FNB; ++f) {
        const int g   = groff + n * FNB + f;
        const int row = msk[g] ? PAD_ROW : src[g];
        const float* sp = emb + (size_t)row * LD + c0;
        *(float4*)&sf[f][0] = *(const float4*)(sp);
        *(float4*)&sf[f][4] = *(const float4*)(sp + 4);
        *(float4*)&sf[f][8] = *(const float4*)(sp + 8);
    }

    float s[FNB * 8];
    #pragma unroll
    for (int h = 0; h < 8; ++h) {
        const float* qp = qky + (size_t)n * QKS + h * LD + c0;
        float qv[12];
        *(float4*)&qv[0] = *(const float4*)(qp);
        *(float4*)&qv[4] = *(const float4*)(qp + 4);
        *(float4*)&qv[8] = *(const float4*)(qp + 8);
        #pragma unroll
        for (int f = 0; f < FNB; ++f) {
            float p = 0.f;
            #pragma unroll
            for (int j = 0; j < 12; ++j) p = fmaf(sf[f][j], qv[j], p);
            s[f * 8 + h] = p;
        }
    }
    #pragma unroll
    for (int i = 0; i < FNB * 8; ++i) {
        float v = s[i];
        v += __shfl_xor(v, 1, 64);  v += __shfl_xor(v, 2, 64);
        v += __shfl_xor(v, 4, 64);  v += __shfl_xor(v, 8, 64);
        v += __shfl_xor(v, 16, 64); v += __shfl_xor(v, 32, 64);
        s[i] = v * 0.10206207262f;            // * 1/sqrt(96)
    }
    #pragma unroll
    for (int h = 0; h < 8; ++h) {             // softmax over f, alpha -> s
        float mx = s[h];
        #pragma unroll
        for (int f = 1; f < FNB; ++f) mx = fmaxf(mx, s[f * 8 + h]);
        float ss = 0.f;
        #pragma unroll
        for (int f = 0; f < FNB; ++f) {
            const float e = __expf(s[f * 8 + h] - mx);
            s[f * 8 + h] = e; ss += e;
        }
        const float inv = 1.f / ss;
        #pragma unroll
        for (int f = 0; f < FNB; ++f) s[f * 8 + h] *= inv;
    }
    #pragma unroll
    for (int h = 0; h < 8; ++h) {             // y = sum_f alpha*sf, in place
        float y[12];
        #pragma unroll
        for (int j = 0; j < 12; ++j) {
            float a = 0.f;
            #pragma unroll
            for (int f = 0; f < FNB; ++f) a = fmaf(s[f * 8 + h], sf[f][j], a);
            y[j] = a;
        }
        float* yp = qky + (size_t)n * QKS + h * LD + c0;
        *(float4*)(yp)     = *(float4*)&y[0];
        *(float4*)(yp + 4) = *(float4*)&y[4];
        *(float4*)(yp + 8) = *(float4*)&y[8];
    }
}

// =====================================================================
// agg[n, h*96+c] (+)= sum_k y[n,h,k] * Wv[k, h*96+c]
// tile 128(n) x 96(c), K=768, head = blockIdx.y, micro-tile 8x6.
// =====================================================================
__global__ __launch_bounds__(256, 2)
void gemm_v(const float* __restrict__ y, const float* __restrict__ Wv,
            float* __restrict__ agg, int accumulate)
{
    __shared__ float As[BKK][132];
    __shared__ float Bs[BKK][104];

    const int tid   = threadIdx.x;
    const int tx    = tid & 15;     // 6 cols each
    const int ty    = tid >> 4;     // 8 rows each
    const int mBase = blockIdx.x * 128;
    const int h     = blockIdx.y;
    const int koff  = h * 96;

    const int arow = tid >> 1;          // 0..127
    const int akc  = (tid & 1) << 3;    // k 0 or 8
    const float* ap = y + (size_t)(mBase + arow) * QKS + (size_t)h * LD + akc;

    int brow[3], bc2[3];
    #pragma unroll
    for (int i = 0; i < 3; ++i) {
        const int f2 = tid * 3 + i;     // 768 float2 per B tile
        brow[i] = f2 / 48;
        bc2[i]  = (f2 % 48) * 2;
    }

    float4 pa0, pa1; float2 pb[3];
    auto loadG = [&](int ks) {
        const int k0 = ks * BKK;
        pa0 = *(const float4*)(ap + k0);
        pa1 = *(const float4*)(ap + k0 + 4);
        #pragma unroll
        for (int i = 0; i < 3; ++i)
            pb[i] = *(const float2*)(Wv + (size_t)(k0 + brow[i]) * LD + koff + bc2[i]);
    };
    auto storeS = [&]() {
        As[akc + 0][arow] = pa0.x; As[akc + 1][arow] = pa0.y;
        As[akc + 2][arow] = pa0.z; As[akc + 3][arow] = pa0.w;
        As[akc + 4][arow] = pa1.x; As[akc + 5][arow] = pa1.y;
        As[akc + 6][arow] = pa1.z; As[akc + 7][arow] = pa1.w;
        #pragma unroll
        for (int i = 0; i < 3; ++i) {
            Bs[brow[i]][bc2[i]]     = pb[i].x;
            Bs[brow[i]][bc2[i] + 1] = pb[i].y;
        }
    };

    float acc[8][6] = {};

    loadG(0); storeS(); __syncthreads();
    for (int ks = 0; ks < KSTEPS; ++ks) {
        const bool more = (ks + 1 < KSTEPS);
        if (more) loadG(ks + 1);
        #pragma unroll
        for (int kk = 0; kk < BKK; ++kk) {
            float a[8], b[6];
            #pragma unroll
            for (int i = 0; i < 8; ++i) a[i] = As[kk][(ty << 3) + i];
            #pragma unroll
            for (int j = 0; j < 6; ++j) b[j] = Bs[kk][tx * 6 + j];
            #pragma unroll
            for (int i = 0; i < 8; ++i)
                #pragma unroll
                for (int j = 0; j < 6; ++j)
                    acc[i][j] = fmaf(a[i], b[j], acc[i][j]);
        }
        __syncthreads();
        if (more) { storeS(); __syncthreads(); }
    }

    float* cp = agg + (size_t)(mBase + (ty << 3)) * LD + koff + tx * 6;
    if (accumulate) {
        #pragma unroll
        for (int i = 0; i < 8; ++i)
            #pragma unroll
            for (int j = 0; j < 6; ++j)
                cp[(size_t)i * LD + j] += acc[i][j];
    } else {
        #pragma unroll
        for (int i = 0; i < 8; ++i) {
            #pragma unroll
            for (int j = 0; j < 3; ++j) {
                float2 v; v.x = acc[i][2 * j]; v.y = acc[i][2 * j + 1];
                *(float2*)(cp + (size_t)i * LD + 2 * j) = v;
            }
        }
    }
}

// =====================================================================
// h = emb_table[ids] row gather
// =====================================================================
__global__ __launch_bounds__(256)
void gather_rows(const float* __restrict__ table, const int* __restrict__ ids,
                 float* __restrict__ outb)
{
    const int i = blockIdx.x * 256 + threadIdx.x;
    const int row = i / 192;
    const int c   = i - row * 192;
    ((float4*)outb)[(size_t)row * 192 + c] =
        ((const float4*)table)[(size_t)ids[row] * 192 + c];
}

// =====================================================================
// h = LayerNorm(h + U) * g + b     (one wave per row)
// =====================================================================
__global__ __launch_bounds__(64)
void ln_residual(float* __restrict__ hbuf, const float* __restrict__ U,
                 const float* __restrict__ g, const float* __restrict__ b)
{
    const int n = blockIdx.x, lane = threadIdx.x;
    float x[12];
    #pragma unroll
    for (int c = 0; c < 3; ++c) {
        const int col = lane * 4 + c * 256;
        const float4 hv = *(const float4*)(hbuf + (size_t)n * LD + col);
        const float4 uv = *(const float4*)(U    + (size_t)n * LD + col);
        x[c*4+0] = hv.x + uv.x; x[c*4+1] = hv.y + uv.y;
        x[c*4+2] = hv.z + uv.z; x[c*4+3] = hv.w + uv.w;
    }
    float s = 0.f;
    #pragma unroll
    for (int t = 0; t < 12; ++t) s += x[t];
    for (int m = 1; m < 64; m <<= 1) s += __shfl_xor(s, m, 64);
    const float mean = s * (1.0f / LD);
    float v = 0.f;
    #pragma unroll
    for (int t = 0; t < 12; ++t) { const float d = x[t] - mean; v = fmaf(d, d, v); }
    for (int m = 1; m < 64; m <<= 1) v += __shfl_xor(v, m, 64);
    const float rinv = rsqrtf(v * (1.0f / LD) + 1e-5f);
    #pragma unroll
    for (int c = 0; c < 3; ++c) {
        const int col = lane * 4 + c * 256;
        const float4 gv = *(const float4*)(g + col);
        const float4 bv = *(const float4*)(b + col);
        float4 yv;
        yv.x = (x[c*4+0] - mean) * rinv * gv.x + bv.x;
        yv.y = (x[c*4+1] - mean) * rinv * gv.y + bv.y;
        yv.z = (x[c*4+2] - mean) * rinv * gv.z + bv.z;
        yv.w = (x[c*4+3] - mean) * rinv * gv.w + bv.w;
        *(float4*)(hbuf + (size_t)n * LD + col) = yv;
    }
}

// =====================================================================
// out[n] = dot(h[n,:], word[n>>3,:])
// =====================================================================
__global__ __launch_bounds__(256)
void final_dot(const float* __restrict__ hbuf, const float* __restrict__ word,
               float* __restrict__ outb)
{
    const int n    = blockIdx.x * 4 + (threadIdx.x >> 6);
    const int lane = threadIdx.x & 63;
    const int bidx = n >> 3;
    float s = 0.f;
    #pragma unroll
    for (int c = 0; c < 3; ++c) {
        const int col = lane * 4 + c * 256;
        const float4 hv = *(const float4*)(hbuf + (size_t)n    * LD + col);
        const float4 wv = *(const float4*)(word + (size_t)bidx * LD + col);
        s = fmaf(hv.x, wv.x, s); s = fmaf(hv.y, wv.y, s);
        s = fmaf(hv.z, wv.z, s); s = fmaf(hv.w, wv.w, s);
    }
    for (int m = 1; m < 64; m <<= 1) s += __shfl_xor(s, m, 64);
    if (lane == 0) outb[n] = s;
}

// =====================================================================
extern "C" void kernel_launch(void* const* d_in, const int* in_sizes, int n_in,
                              void* d_out, int out_size, void* d_ws, size_t ws_size,
                              hipStream_t stream)
{
    (void)in_sizes; (void)n_in; (void)out_size;
    const float* emb      = (const float*)d_in[0];
    const float* aver     = (const float*)d_in[1];
    const float* Wt       = (const float*)d_in[2];
    const float* Wq       = (const float*)d_in[3];
    const float* Wk       = (const float*)d_in[4];
    const float* Wv       = (const float*)d_in[5];
    const float* Wo       = (const float*)d_in[6];
    const float* ln_g     = (const float*)d_in[7];
    const float* ln_b     = (const float*)d_in[8];
    const int*   id_pairs = (const int*)d_in[9];
    const int*   src_ids  = (const int*)d_in[10];
    const void*  mask_raw = d_in[11];
    float* outp = (float*)d_out;

    // ---- workspace carve ----
    char* wp = (char*)d_ws;
    int* mflag = (int*)wp;                      wp += 4096;
    unsigned char* mcanon = (unsigned char*)wp; wp += 164096;
    const size_t head_bytes = 4096 + 164096;

    // per-node bytes: word 384 + h 3072 + Q 3072 + agg 3072 + qky 24576 = 34176
    int NC = NTOT;
    while (NC > 1024 && head_bytes + (size_t)NC * 34176 > ws_size) NC >>= 1;

    float* wordb = (float*)wp; wp += (size_t)(NC / 8) * LD * 4;
    float* hb    = (float*)wp; wp += (size_t)NC * LD * 4;
    float* Qb    = (float*)wp; wp += (size_t)NC * LD * 4;    // also holds U
    float* aggb  = (float*)wp; wp += (size_t)NC * LD * 4;
    float* qky   = (float*)wp;                                // [NC, 8, 768]

    detect_mask<<<1, 256, 0, stream>>>((const unsigned int*)mask_raw, mflag);
    canon_mask<<<MASK_N / 256, 256, 0, stream>>>(mask_raw, mflag, mcanon);

    for (int c0 = 0; c0 < NTOT; c0 += NC) {
        gemm_f32<true><<<dim3((NC / 8) / 128, 6), 256, 0, stream>>>(
            aver + (size_t)(c0 / 8) * LD, Wt, wordb);
        gather_rows<<<(NC * (LD / 4)) / 256, 256, 0, stream>>>(
            emb, id_pairs + c0, hb);

        for (int l = 0; l < 2; ++l) {
            for (int r = 0; r < 2; ++r) {
                const float* wq = Wq + (size_t)(l * 2 + r) * LD * LD;
                const float* wk = Wk + (size_t)(l * 2 + r) * LD * LD;
                const float* wv = Wv + (size_t)(l * 2 + r) * LD * LD;
                const int groff = r * NTOT * FNB + c0 * FNB;

                // Q = h @ Wq
                gemm_f32<false><<<dim3(NC / 128, 6), 256, 0, stream>>>(hb, wq, Qb);
                // qk[n,h,c] = Q_h @ Wk_h^T   (K=96 per head)
                gemm_qk<<<dim3(NC / 128, 6, 8), 256, 0, stream>>>(Qb, wk, qky);
                // scores -> softmax -> y (in place over qk)
                scores_y<<<NC / 4, 256, 0, stream>>>(emb, src_ids, mcanon, groff, qky);
                // agg (+)= y_h @ Wv_h
                gemm_v<<<dim3(NC / 128, 8), 256, 0, stream>>>(qky, wv, aggb, r);
            }
            gemm_f32<false><<<dim3(NC / 128, 6), 256, 0, stream>>>(
                aggb, Wo + (size_t)l * LD * LD, Qb);
            ln_residual<<<NC, 64, 0, stream>>>(hb, Qb, ln_g + (size_t)l * LD,
                                               ln_b + (size_t)l * LD);
        }

        final_dot<<<NC / 4, 256, 0, stream>>>(hb, wordb, outp + c0);
    }
}